// Round 8
// baseline (536.448 us; speedup 1.0000x reference)
//
#include <hip/hip_runtime.h>
#include <hip/hip_fp16.h>

#define TLEN 512
#define HDIM 32
#define FOUT 20
#define HST  40   // 80B rows; with 8 rows the b128 spans tile all 32 banks (rows*20 dwords mod 32
                  // = 0,20,8,28,16,4,24,12), lanes 8-15 broadcast same addr -> conflict-light.

typedef __attribute__((ext_vector_type(8))) short bf16x8;
typedef __attribute__((ext_vector_type(4))) float f32x4;
typedef __attribute__((ext_vector_type(4))) short s16x4;

__device__ __forceinline__ float sigm(float v) {
  float e = __builtin_amdgcn_exp2f(-1.4426950408889634f * v);
  return __builtin_amdgcn_rcpf(1.0f + e);
}
__device__ __forceinline__ float tanh_f(float v) {
  float e = __builtin_amdgcn_exp2f(2.8853900817779268f * v);
  return 1.0f - 2.0f * __builtin_amdgcn_rcpf(1.0f + e);
}
// round-to-nearest-even bf16 hi/lo split: v ~= hi + lo (~16-bit mantissa coverage)
__device__ __forceinline__ void hilo(float v, short& h, short& l) {
  unsigned u = __builtin_bit_cast(unsigned, v);
  unsigned r = u + 0x7fffu + ((u >> 16) & 1u);
  h = (short)(r >> 16);
  float hf = __builtin_bit_cast(float, r & 0xffff0000u);
  float res = v - hf;
  unsigned u2 = __builtin_bit_cast(unsigned, res);
  unsigned r2 = u2 + 0x7fffu + ((u2 >> 16) & 1u);
  l = (short)(r2 >> 16);
}

// Barrier draining only LDS (lgkmcnt) — global output stores keep flowing.
__device__ __forceinline__ void barrier_lgkm() {
  asm volatile("s_waitcnt lgkmcnt(0)\n\ts_barrier" ::: "memory");
}

// one 16B-aligned ds_read_b128 -> one bf16x8 fragment
__device__ __forceinline__ bf16x8 read_h(const short* buf, int off) {
  return *(const bf16x8*)(buf + off);
}

// gates in regs: g[0..3] = i,f,g,o for ONE (batch,unit) position
__device__ __forceinline__ float lstm_update(const f32x4& g, float& c) {
  float iv = sigm(g[0]), fv = sigm(g[1]), gv = tanh_f(g[2]), ov = sigm(g[3]);
  c = fv * c + iv * gv;
  return ov * tanh_f(c);
}

// TWO BARRIER DOMAINS PER CU (this round's single variable):
// 512 blocks x 8 waves, 8 batch rows per block -> 2 independent blocks co-resident
// per CU; block A's barrier/drain stall overlaps block B's compute.
//   waves 0-3 = L1 (two 4-unit M-tiles each: units 8wr..8wr+7), 6 MFMA
//   waves 4-7 = L2 (two M-tiles), 12 MFMA + out-proj duty (2 pairs, every 2nd step)
// Half-width N handled by DUPLICATED B-frag addressing: aoff=(n&7)*HST+q8 makes
// C cols 8-15 replicate batches 0-7, so lane n<8 takes tile0's C (batch n) and
// lane n>=8 takes tile1's C (batch n-8): one update per lane, no cross-lane moves,
// per-CU VALU/trans issue unchanged. Per-chain MFMA order identical -> bit-identical.
__global__ __launch_bounds__(512, 4) void lstm_seq_kernel(
    const float* __restrict__ xg,
    const float* __restrict__ Wih1, const float* __restrict__ Whh1,
    const float* __restrict__ bih1, const float* __restrict__ bhh1,
    const float* __restrict__ Wih2, const float* __restrict__ Whh2,
    const float* __restrict__ bih2, const float* __restrict__ bhh2,
    const float* __restrict__ Wout, const float* __restrict__ bout,
    float* __restrict__ out)
{
  __shared__ __half xl[8 * 1028];                          // x staged fp16 (8 rows)
  __shared__ short h1hiB[2][8 * HST], h1loB[2][8 * HST];   // ping-pong h buffers
  __shared__ short h2hiB[2][8 * HST], h2loB[2][8 * HST];

  const int tid  = threadIdx.x;
  const int w    = tid >> 6;     // wave 0..7
  const int lane = tid & 63;
  const int n    = lane & 15;    // A-row (weights) / C col; batch = n&7
  const int q    = lane >> 4;    // quad
  const int q4   = q * 4;
  const int q8   = q * 8;
  const int b0   = blockIdx.x * 8;
  const bool isL1 = (w < 4);
  const int wr   = w & 3;        // role-local tile-group 0..3 (units 8wr..8wr+7)
  const int ub   = wr * 8;
  const int p    = w & 1;        // out-proj tile (rows 16p..16p+15), L2 waves only
  const int pr   = (w >> 1) & 1; // out-proj duty pair 0..1, L2 waves only
  const bool hiHalf = (n & 8) != 0;

  // ---- stage x[b0..b0+7][0..1024) into LDS as fp16 (coalesced)
  for (int idx = tid; idx < 8 * 1024; idx += 512) {
    int row = idx >> 10, col = idx & 1023;
    xl[row * 1028 + col] = __float2half(xg[((size_t)(b0 + row) << 10) + col]);
  }

  // ---- weight A-frags for BOTH tiles: A-row m=lane&15 -> gate m&3, unit-in-tile m>>2
  const int og0 = (n & 3) * HDIM + ub + (n >> 2);
  const int og1 = og0 + 4;
  bf16x8 WA0h, WA0l, WA1h, WA1l;          // L1: Whh1. L2: Wih2
  bf16x8 WB0h = {0,0,0,0,0,0,0,0}, WB0l = {0,0,0,0,0,0,0,0};  // L2: Whh2
  bf16x8 WB1h = {0,0,0,0,0,0,0,0}, WB1l = {0,0,0,0,0,0,0,0};
  float bc0[4], bc1[4], wx00[4], wx10[4], wx01[4], wx11[4];
  f32x4 bcv0 = {0.f,0.f,0.f,0.f}, bcv1 = {0.f,0.f,0.f,0.f};
  f32x4 bocv = {0.f,0.f,0.f,0.f};
  const f32x4 zv4 = {0.f,0.f,0.f,0.f};
  bf16x8 WoH = {0,0,0,0,0,0,0,0}, WoL = {0,0,0,0,0,0,0,0};
  if (isL1) {
    #pragma unroll
    for (int j = 0; j < 8; j++) {
      short hh, ll;
      hilo(Whh1[og0 * HDIM + q8 + j], hh, ll); WA0h[j] = hh; WA0l[j] = ll;
      hilo(Whh1[og1 * HDIM + q8 + j], hh, ll); WA1h[j] = hh; WA1l[j] = ll;
    }
    #pragma unroll
    for (int r = 0; r < 4; r++) {
      int gr0 = r * HDIM + ub + q, gr1 = gr0 + 4;
      bc0[r]  = bih1[gr0] + bhh1[gr0];  bc1[r]  = bih1[gr1] + bhh1[gr1];
      wx00[r] = Wih1[gr0 * 2 + 0];      wx01[r] = Wih1[gr1 * 2 + 0];
      wx10[r] = Wih1[gr0 * 2 + 1];      wx11[r] = Wih1[gr1 * 2 + 1];
    }
  } else {
    #pragma unroll
    for (int j = 0; j < 8; j++) {
      short hh, ll;
      hilo(Wih2[og0 * HDIM + q8 + j], hh, ll); WA0h[j] = hh; WA0l[j] = ll;
      hilo(Wih2[og1 * HDIM + q8 + j], hh, ll); WA1h[j] = hh; WA1l[j] = ll;
      hilo(Whh2[og0 * HDIM + q8 + j], hh, ll); WB0h[j] = hh; WB0l[j] = ll;
      hilo(Whh2[og1 * HDIM + q8 + j], hh, ll); WB1h[j] = hh; WB1l[j] = ll;
    }
    #pragma unroll
    for (int r = 0; r < 4; r++) {
      int gr0 = r * HDIM + ub + q, gr1 = gr0 + 4;
      bcv0[r] = bih2[gr0] + bhh2[gr0];
      bcv1[r] = bih2[gr1] + bhh2[gr1];
      int orow = 16 * p + q4 + r;
      bocv[r] = (orow < FOUT) ? bout[orow] : 0.0f;
    }
    int orow = 16 * p + n;
    if (orow < FOUT) {
      #pragma unroll
      for (int j = 0; j < 8; j++) {
        short hh, ll;
        hilo(Wout[orow * HDIM + q8 + j], hh, ll); WoH[j] = hh; WoL[j] = ll;
      }
    }
  }

  // lane's own update position: batch n&7, unit ub + (hiHalf?4:0) + q
  const int hoff = (n & 7) * HST + ub + (hiHalf ? 4 : 0) + q;
  const int aoff = (n & 7) * HST + q8;   // duplicated-batch B-frag (16B aligned)
  float c = 0.0f;                        // c1 on L1 waves, c2 on L2 waves

  bf16x8 h1h = {0,0,0,0,0,0,0,0}, h1l = {0,0,0,0,0,0,0,0};
  bf16x8 h2h = {0,0,0,0,0,0,0,0}, h2l = {0,0,0,0,0,0,0,0};

  __syncthreads();   // x staging visible (full barrier once)

  // ================= head: t = 0 (L1 only; h1(-1)=0 -> pure VALU, no MFMA)
  if (isL1) {
    __half2 hv = *(const __half2*)&xl[(n & 7) * 1028];
    float xv0 = __half2float(hv.x), xv1 = __half2float(hv.y);
    f32x4 g1;
    #pragma unroll
    for (int r = 0; r < 4; r++) {
      float b  = hiHalf ? bc1[r]  : bc0[r];
      float w0 = hiHalf ? wx01[r] : wx00[r];
      float w1 = hiHalf ? wx11[r] : wx10[r];
      g1[r] = fmaf(xv1, w1, fmaf(xv0, w0, b));
    }
    float h1n = lstm_update(g1, c);
    short hh, ll; hilo(h1n, hh, ll);
    h1hiB[0][hoff] = hh; h1loB[0][hoff] = ll;
  }
  barrier_lgkm();
  h1h = read_h(h1hiB[0], aoff);   // all waves: h1(0); L2's h2 regs = h2(-1) = 0
  h1l = read_h(h1loB[0], aoff);

  // ================= STEP macro: iter T computes L1(T) / L2(T-1); PAR = T&1;
  // DS1 = duty slot (T&1, or -1 before s=0). Duty pair pr==DS1 emits s=T-2 from
  // STALE h2 regs (read at T-1) post-barrier, before the re-read. Compile-time slots.
#define STEP(T, PAR, DS1, XV0, XV1)                                               \
  {                                                                               \
    if (isL1) {                                                                   \
      f32x4 g1t0, g1t1;                                                           \
      _Pragma("unroll") for (int r = 0; r < 4; r++) {                             \
        g1t0[r] = fmaf((XV1), wx10[r], fmaf((XV0), wx00[r], bc0[r]));             \
        g1t1[r] = fmaf((XV1), wx11[r], fmaf((XV0), wx01[r], bc1[r]));             \
      }                                                                           \
      g1t0 = __builtin_amdgcn_mfma_f32_16x16x32_bf16(WA0h, h1h, g1t0, 0, 0, 0);   \
      g1t1 = __builtin_amdgcn_mfma_f32_16x16x32_bf16(WA1h, h1h, g1t1, 0, 0, 0);   \
      g1t0 = __builtin_amdgcn_mfma_f32_16x16x32_bf16(WA0l, h1h, g1t0, 0, 0, 0);   \
      g1t1 = __builtin_amdgcn_mfma_f32_16x16x32_bf16(WA1l, h1h, g1t1, 0, 0, 0);   \
      g1t0 = __builtin_amdgcn_mfma_f32_16x16x32_bf16(WA0h, h1l, g1t0, 0, 0, 0);   \
      g1t1 = __builtin_amdgcn_mfma_f32_16x16x32_bf16(WA1h, h1l, g1t1, 0, 0, 0);   \
      f32x4 g;                                                                    \
      _Pragma("unroll") for (int r = 0; r < 4; r++)                               \
        g[r] = hiHalf ? g1t1[r] : g1t0[r];                                        \
      float h1n = lstm_update(g, c);                                              \
      short hh, ll; hilo(h1n, hh, ll);                                            \
      h1hiB[PAR][hoff] = hh; h1loB[PAR][hoff] = ll;                               \
    } else {                                                                      \
      f32x4 ga0 = __builtin_amdgcn_mfma_f32_16x16x32_bf16(WA0h, h1h, bcv0, 0, 0, 0); \
      f32x4 gb0 = __builtin_amdgcn_mfma_f32_16x16x32_bf16(WB0h, h2h, zv4, 0, 0, 0);  \
      f32x4 ga1 = __builtin_amdgcn_mfma_f32_16x16x32_bf16(WA1h, h1h, bcv1, 0, 0, 0); \
      f32x4 gb1 = __builtin_amdgcn_mfma_f32_16x16x32_bf16(WB1h, h2h, zv4, 0, 0, 0);  \
      ga0 = __builtin_amdgcn_mfma_f32_16x16x32_bf16(WA0l, h1h, ga0, 0, 0, 0);     \
      gb0 = __builtin_amdgcn_mfma_f32_16x16x32_bf16(WB0l, h2h, gb0, 0, 0, 0);     \
      ga1 = __builtin_amdgcn_mfma_f32_16x16x32_bf16(WA1l, h1h, ga1, 0, 0, 0);     \
      gb1 = __builtin_amdgcn_mfma_f32_16x16x32_bf16(WB1l, h2h, gb1, 0, 0, 0);     \
      ga0 = __builtin_amdgcn_mfma_f32_16x16x32_bf16(WA0h, h1l, ga0, 0, 0, 0);     \
      gb0 = __builtin_amdgcn_mfma_f32_16x16x32_bf16(WB0h, h2l, gb0, 0, 0, 0);     \
      ga1 = __builtin_amdgcn_mfma_f32_16x16x32_bf16(WA1h, h1l, ga1, 0, 0, 0);     \
      gb1 = __builtin_amdgcn_mfma_f32_16x16x32_bf16(WB1h, h2l, gb1, 0, 0, 0);     \
      f32x4 g;                                                                    \
      _Pragma("unroll") for (int r = 0; r < 4; r++) {                             \
        float t0 = ga0[r] + gb0[r];                                               \
        float t1 = ga1[r] + gb1[r];                                               \
        g[r] = hiHalf ? t1 : t0;                                                  \
      }                                                                           \
      float h2n = lstm_update(g, c);                                              \
      short hh, ll; hilo(h2n, hh, ll);                                            \
      h2hiB[PAR][hoff] = hh; h2loB[PAR][hoff] = ll;                               \
    }                                                                             \
    barrier_lgkm();   /* h1(T), h2(T-1) visible */                                \
    if (isL1) {                                                                   \
      h1h = read_h(h1hiB[PAR], aoff);                                             \
      h1l = read_h(h1loB[PAR], aoff);                                             \
    } else {                                                                      \
      if ((DS1) >= 0 && pr == (DS1)) {                                            \
        f32x4 ao = __builtin_amdgcn_mfma_f32_16x16x32_bf16(WoH, h2h, bocv, 0, 0, 0); \
        ao = __builtin_amdgcn_mfma_f32_16x16x32_bf16(WoL, h2h, ao, 0, 0, 0);      \
        ao = __builtin_amdgcn_mfma_f32_16x16x32_bf16(WoH, h2l, ao, 0, 0, 0);      \
        if ((p == 0 || q == 0) && n < 8) {                                        \
          float4 st = { ao[0], ao[1], ao[2], ao[3] };                             \
          *(float4*)&out[((size_t)(b0 + n) * TLEN + ((T) - 2)) * FOUT + 16 * p + q4] = st; \
        }                                                                         \
      }                                                                           \
      h1h = read_h(h1hiB[PAR], aoff);                                             \
      h1l = read_h(h1loB[PAR], aoff);                                             \
      h2h = read_h(h2hiB[PAR], aoff);                                             \
      h2l = read_h(h2loB[PAR], aoff);                                             \
    }                                                                             \
  }

  // ================= peel: t = 1, 2, 3 (compile-time constants)
  {
    float a0 = 0.f, a1 = 0.f;
    if (isL1) { __half2 hv = *(const __half2*)&xl[(n & 7) * 1028 + 2]; a0 = __half2float(hv.x); a1 = __half2float(hv.y); }
    STEP(1, 1, -1, a0, a1);
    if (isL1) { __half2 hv = *(const __half2*)&xl[(n & 7) * 1028 + 4]; a0 = __half2float(hv.x); a1 = __half2float(hv.y); }
    STEP(2, 0, 0, a0, a1);
    if (isL1) { __half2 hv = *(const __half2*)&xl[(n & 7) * 1028 + 6]; a0 = __half2float(hv.x); a1 = __half2float(hv.y); }
    STEP(3, 1, 1, a0, a1);
  }

  // ================= main: 4x unrolled, t = 4..511 (127 groups)
  float xv[8] = {0.f, 0.f, 0.f, 0.f, 0.f, 0.f, 0.f, 0.f};
  for (int t = 4; t < TLEN; t += 4) {
    if (isL1) {
      const short* xp = (const short*)xl + (n & 7) * 1028 + 2 * t;   // 8B-aligned
      s16x4 xa = *(const s16x4*)xp;
      s16x4 xb = *(const s16x4*)(xp + 4);
      #pragma unroll
      for (int j = 0; j < 4; j++) {
        xv[j]     = __half2float(__builtin_bit_cast(__half, (short)xa[j]));
        xv[4 + j] = __half2float(__builtin_bit_cast(__half, (short)xb[j]));
      }
    }
    STEP(t + 0, 0, 0, xv[0], xv[1]);
    STEP(t + 1, 1, 1, xv[2], xv[3]);
    STEP(t + 2, 0, 0, xv[4], xv[5]);
    STEP(t + 3, 1, 1, xv[6], xv[7]);
  }
#undef STEP

  // ================= epilogue E1 (T=512): L2 computes h2(511)
  // (h1 regs = h1(511), h2 regs = h2(510), read at post-T=511)
  if (!isL1) {
    f32x4 ga0 = __builtin_amdgcn_mfma_f32_16x16x32_bf16(WA0h, h1h, bcv0, 0, 0, 0);
    f32x4 gb0 = __builtin_amdgcn_mfma_f32_16x16x32_bf16(WB0h, h2h, zv4, 0, 0, 0);
    f32x4 ga1 = __builtin_amdgcn_mfma_f32_16x16x32_bf16(WA1h, h1h, bcv1, 0, 0, 0);
    f32x4 gb1 = __builtin_amdgcn_mfma_f32_16x16x32_bf16(WB1h, h2h, zv4, 0, 0, 0);
    ga0 = __builtin_amdgcn_mfma_f32_16x16x32_bf16(WA0l, h1h, ga0, 0, 0, 0);
    gb0 = __builtin_amdgcn_mfma_f32_16x16x32_bf16(WB0l, h2h, gb0, 0, 0, 0);
    ga1 = __builtin_amdgcn_mfma_f32_16x16x32_bf16(WA1l, h1h, ga1, 0, 0, 0);
    gb1 = __builtin_amdgcn_mfma_f32_16x16x32_bf16(WB1l, h2h, gb1, 0, 0, 0);
    ga0 = __builtin_amdgcn_mfma_f32_16x16x32_bf16(WA0h, h1l, ga0, 0, 0, 0);
    gb0 = __builtin_amdgcn_mfma_f32_16x16x32_bf16(WB0h, h2l, gb0, 0, 0, 0);
    ga1 = __builtin_amdgcn_mfma_f32_16x16x32_bf16(WA1h, h1l, ga1, 0, 0, 0);
    gb1 = __builtin_amdgcn_mfma_f32_16x16x32_bf16(WB1h, h2l, gb1, 0, 0, 0);
    f32x4 g;
    #pragma unroll
    for (int r = 0; r < 4; r++) {
      float t0 = ga0[r] + gb0[r];
      float t1 = ga1[r] + gb1[r];
      g[r] = hiHalf ? t1 : t0;
    }
    float h2n = lstm_update(g, c);
    short hh, ll; hilo(h2n, hh, ll);
    h2hiB[0][hoff] = hh; h2loB[0][hoff] = ll;
  }
  barrier_lgkm();
  if (!isL1) {
    if (pr == 0) {                  // s = 510 (510&1==0): stale regs = h2(510)
      const int s = TLEN - 2;
      f32x4 ao = __builtin_amdgcn_mfma_f32_16x16x32_bf16(WoH, h2h, bocv, 0, 0, 0);
      ao = __builtin_amdgcn_mfma_f32_16x16x32_bf16(WoL, h2h, ao, 0, 0, 0);
      ao = __builtin_amdgcn_mfma_f32_16x16x32_bf16(WoH, h2l, ao, 0, 0, 0);
      if ((p == 0 || q == 0) && n < 8) {
        float4 st = { ao[0], ao[1], ao[2], ao[3] };
        *(float4*)&out[((size_t)(b0 + n) * TLEN + s) * FOUT + 16 * p + q4] = st;
      }
    }
    if (pr == 1) {                  // s = 511: read fresh h2(511)
      h2h = read_h(h2hiB[0], aoff);
      h2l = read_h(h2loB[0], aoff);
      const int s = TLEN - 1;
      f32x4 ao = __builtin_amdgcn_mfma_f32_16x16x32_bf16(WoH, h2h, bocv, 0, 0, 0);
      ao = __builtin_amdgcn_mfma_f32_16x16x32_bf16(WoL, h2h, ao, 0, 0, 0);
      ao = __builtin_amdgcn_mfma_f32_16x16x32_bf16(WoH, h2l, ao, 0, 0, 0);
      if ((p == 0 || q == 0) && n < 8) {
        float4 st = { ao[0], ao[1], ao[2], ao[3] };
        *(float4*)&out[((size_t)(b0 + n) * TLEN + s) * FOUT + 16 * p + q4] = st;
      }
    }
  }
}

extern "C" void kernel_launch(void* const* d_in, const int* in_sizes, int n_in,
                              void* d_out, int out_size, void* d_ws, size_t ws_size,
                              hipStream_t stream) {
  const float* xg   = (const float*)d_in[0];
  const float* Wih1 = (const float*)d_in[1];
  const float* Whh1 = (const float*)d_in[2];
  const float* bih1 = (const float*)d_in[3];
  const float* bhh1 = (const float*)d_in[4];
  const float* Wih2 = (const float*)d_in[5];
  const float* Whh2 = (const float*)d_in[6];
  const float* bih2 = (const float*)d_in[7];
  const float* bhh2 = (const float*)d_in[8];
  const float* Wout = (const float*)d_in[9];
  const float* bout = (const float*)d_in[10];
  float* out = (float*)d_out;

  hipLaunchKernelGGL(lstm_seq_kernel, dim3(512), dim3(512), 0, stream,
                     xg, Wih1, Whh1, bih1, bhh1, Wih2, Whh2, bih2, bhh2, Wout, bout, out);
}